// Round 5
// baseline (239.958 us; speedup 1.0000x reference)
//
#include <hip/hip_runtime.h>
#include <cstddef>

#define B_  16
#define C_  512
#define N_  1024
// 0.125 * log2(e): folded into Q in the QKV GEMM epilogue; attn uses exp2.
#define QSC 0.18033688011112042f

typedef __attribute__((ext_vector_type(8))) __bf16 bf16x8;
typedef __attribute__((ext_vector_type(4))) float f32x4;

__device__ __forceinline__ unsigned short f2bf(float x) {
  unsigned u = __float_as_uint(x);
  return (unsigned short)((u + 0x7fffu + ((u >> 16) & 1u)) >> 16);
}

#define GLDS16(g, l)                                                            \
  __builtin_amdgcn_global_load_lds(                                             \
      (const __attribute__((address_space(1))) void*)(g),                       \
      (__attribute__((address_space(3))) void*)(l), 16, 0, 0)

// ---------- weight fp32 -> bf16 ----------
__global__ __launch_bounds__(256) void wconv_kernel(
    const float* __restrict__ wq, const float* __restrict__ wp,
    unsigned short* __restrict__ oq, unsigned short* __restrict__ op) {
  int i = blockIdx.x * 256 + threadIdx.x;
  const float4* src; unsigned short* dst; int off;
  if (i < 196608) { src = (const float4*)wq; dst = oq; off = i; }
  else            { src = (const float4*)wp; dst = op; off = i - 196608; }
  float4 v = src[off];
  union { unsigned short s[4]; ushort4 u; } o;
  o.s[0] = f2bf(v.x); o.s[1] = f2bf(v.y);
  o.s[2] = f2bf(v.z); o.s[3] = f2bf(v.w);
  *(ushort4*)(dst + (size_t)off * 4) = o.u;
}

// ---------- GroupNorm: writes hT[b][n][c] bf16 ----------
__global__ __launch_bounds__(256) void gn_kernel(
    const float* __restrict__ x, const float* __restrict__ gamma,
    const float* __restrict__ beta, unsigned short* __restrict__ hT) {
  int bg = blockIdx.x;
  int b = bg >> 5, g = bg & 31;
  size_t base = ((size_t)b * C_ + (size_t)g * 16) * N_;
  const float4* x4 = (const float4*)(x + base);
  int tid = threadIdx.x;

  float sum = 0.f, sq = 0.f;
  float4 vv[16];
#pragma unroll
  for (int i = 0; i < 16; i++) {
    float4 v = x4[tid + i * 256];
    vv[i] = v;
    sum += v.x + v.y + v.z + v.w;
    sq  += v.x * v.x + v.y * v.y + v.z * v.z + v.w * v.w;
  }
#pragma unroll
  for (int off = 32; off > 0; off >>= 1) {
    sum += __shfl_down(sum, off, 64);
    sq  += __shfl_down(sq, off, 64);
  }
  __shared__ float sm[4], sv[4];
  int lane = tid & 63, w = tid >> 6;
  if (lane == 0) { sm[w] = sum; sv[w] = sq; }
  __syncthreads();
  if (tid == 0) {
    float s = sm[0] + sm[1] + sm[2] + sm[3];
    float q = sv[0] + sv[1] + sv[2] + sv[3];
    float mean = s * (1.f / 16384.f);
    float var  = q * (1.f / 16384.f) - mean * mean;
    sm[0] = mean;
    sv[0] = rsqrtf(var + 1e-5f);
  }
  __syncthreads();
  float mean = sm[0], rstd = sv[0];

  union { unsigned short s[16]; uint4 u[2]; } row[4];
#pragma unroll
  for (int i = 0; i < 16; i++) {
    int c = g * 16 + i;
    float ga = gamma[c] * rstd;
    float be = beta[c] - mean * ga;
    float4 v = vv[i];
    row[0].s[i] = f2bf(v.x * ga + be);
    row[1].s[i] = f2bf(v.y * ga + be);
    row[2].s[i] = f2bf(v.z * ga + be);
    row[3].s[i] = f2bf(v.w * ga + be);
  }
#pragma unroll
  for (int j = 0; j < 4; j++) {
    uint4* dst = (uint4*)(hT + ((size_t)b * N_ + 4 * tid + j) * C_ + g * 16);
    dst[0] = row[j].u[0];
    dst[1] = row[j].u[1];
  }
}

// ---------- MFMA GEMM, m97 structure ----------
// MODE 0 (proj): fp32 Out[b,m,n] = acc + bias + resid.
// MODE 1 (qkv):  blockIdx.y<8 -> bf16 transposed qkT[b][n][m] (Q rows scaled
//                by QSC); else bf16 natural Vb[b][m-1024][n].
template <int MODE>
__global__ __launch_bounds__(256) void gemm_mfma(
    const unsigned short* __restrict__ Wb, const float* __restrict__ bias,
    const unsigned short* __restrict__ InT, const float* __restrict__ resid,
    void* __restrict__ Out, void* __restrict__ Out2, int M) {
  __shared__ __align__(16) unsigned short As[128 * 32];
  __shared__ __align__(16) unsigned short Bs[128 * 32];

  const int b = blockIdx.z;
  const int n0 = blockIdx.x * 128, m0 = blockIdx.y * 128;
  const int tid = threadIdx.x;
  const int lane = tid & 63, wave = tid >> 6;
  const int col = lane & 15, quad = lane >> 4;
  const int wm = (wave >> 1) << 6, wn = (wave & 1) << 6;

  const unsigned short* Ag = Wb + (size_t)m0 * C_;
  const unsigned short* Bg = InT + ((size_t)b * N_ + n0) * C_;

  const int r0 = tid >> 2, c0 = (tid & 3) << 3;

  f32x4 acc[4][4];
#pragma unroll
  for (int i = 0; i < 4; i++)
#pragma unroll
    for (int j = 0; j < 4; j++) acc[i][j] = f32x4{0.f, 0.f, 0.f, 0.f};

  for (int k0 = 0; k0 < C_; k0 += 32) {
    __syncthreads();
    GLDS16(Ag + (size_t)r0 * C_ + k0 + c0,        &As[tid * 8]);
    GLDS16(Ag + (size_t)(r0 + 64) * C_ + k0 + c0, &As[(tid + 256) * 8]);
    GLDS16(Bg + (size_t)r0 * C_ + k0 + c0,        &Bs[tid * 8]);
    GLDS16(Bg + (size_t)(r0 + 64) * C_ + k0 + c0, &Bs[(tid + 256) * 8]);
    __syncthreads();

    bf16x8 af[4], bfr[4];
#pragma unroll
    for (int mt = 0; mt < 4; mt++)
      af[mt] = *(const bf16x8*)&As[(wm + mt * 16 + col) * 32 + quad * 8];
#pragma unroll
    for (int nt = 0; nt < 4; nt++)
      bfr[nt] = *(const bf16x8*)&Bs[(wn + nt * 16 + col) * 32 + quad * 8];
#pragma unroll
    for (int mt = 0; mt < 4; mt++)
#pragma unroll
      for (int nt = 0; nt < 4; nt++)
        acc[mt][nt] = __builtin_amdgcn_mfma_f32_16x16x32_bf16(
            af[mt], bfr[nt], acc[mt][nt], 0, 0, 0);
  }

  if constexpr (MODE == 0) {
#pragma unroll
    for (int mt = 0; mt < 4; mt++) {
      int mbase = m0 + wm + mt * 16 + quad * 4;
#pragma unroll
      for (int nt = 0; nt < 4; nt++) {
        int n = n0 + wn + nt * 16 + col;
#pragma unroll
        for (int r = 0; r < 4; r++) {
          int m = mbase + r;
          size_t off = ((size_t)b * M + m) * N_ + n;
          ((float*)Out)[off] = acc[mt][nt][r] + bias[m] + resid[off];
        }
      }
    }
  } else {
    if (blockIdx.y < 8) {  // Q or K -> transposed qkT[b][n][1024]
      float qs = (blockIdx.y < 4) ? QSC : 1.0f;
#pragma unroll
      for (int mt = 0; mt < 4; mt++) {
        int mbase = m0 + wm + mt * 16 + quad * 4;
#pragma unroll
        for (int nt = 0; nt < 4; nt++) {
          int n = n0 + wn + nt * 16 + col;
          union { unsigned short s[4]; ushort4 v; } o;
#pragma unroll
          for (int r = 0; r < 4; r++)
            o.s[r] = f2bf((acc[mt][nt][r] + bias[mbase + r]) * qs);
          *(ushort4*)((unsigned short*)Out + ((size_t)b * N_ + n) * 1024 + mbase) = o.v;
        }
      }
    } else {  // V -> natural Vb[b][m-1024][n]
#pragma unroll
      for (int mt = 0; mt < 4; mt++) {
        int mbase = m0 + wm + mt * 16 + quad * 4;
#pragma unroll
        for (int nt = 0; nt < 4; nt++) {
          int n = n0 + wn + nt * 16 + col;
#pragma unroll
          for (int r = 0; r < 4; r++) {
            int m = mbase + r;
            ((unsigned short*)Out2)[((size_t)b * 512 + (m - 1024)) * N_ + n] =
                f2bf(acc[mt][nt][r] + bias[m]);
          }
        }
      }
    }
  }
}

// ---------- MFMA flash attention v3 ----------
// Q,K read directly from qkT[b][n][1024] (d-contiguous, 16B loads).
// V DMA'd into LDS (double-buffered, XOR-chunk swizzle), read as b128.
// S^T tiles use permuted key rows so their packed exp C-regs concatenate into
// full-rate 16x16x32 PV B-fragments (no cross-lane movement).
__global__ __launch_bounds__(256) void attn_mfma(
    const unsigned short* __restrict__ qkT, const unsigned short* __restrict__ Vb,
    unsigned short* __restrict__ aoT) {
  __shared__ __align__(16) unsigned short Vs[2][64 * 64];

  const int tid = threadIdx.x;
  const int wave = tid >> 6, lane = tid & 63;
  const int quad = lane >> 4, col = lane & 15;
  const int b = blockIdx.z, hh = blockIdx.y;
  const int qblk = blockIdx.x * 256 + wave * 64;

  const unsigned short* qkrow = qkT + (size_t)b * N_ * 1024;
  const unsigned short* vp = Vb + ((size_t)b * 512 + hh * 64) * N_;

  // Q B-fragments (pre-scaled by QSC in GEMM): 16B loads.
  bf16x8 qf[4][2];
#pragma unroll
  for (int nt = 0; nt < 4; nt++) {
    const unsigned short* qr = qkrow + (size_t)(qblk + nt * 16 + col) * 1024 + hh * 64;
#pragma unroll
    for (int ks = 0; ks < 2; ks++)
      qf[nt][ks] = *(const bf16x8*)(qr + ks * 32 + quad * 8);
  }

  // permuted key row (within 32-key segment) for S-tile u: keys s.t. the
  // packed exp C-regs form the x32 PV B-fragment directly.
  const int krow_base = 8 * (col >> 2) + (col & 3);  // + 4*(u&1) + 32*(u>>1)

  float l_i[4];
  f32x4 O[4][4];
#pragma unroll
  for (int nt = 0; nt < 4; nt++) {
    l_i[nt] = 0.f;
#pragma unroll
    for (int mt = 0; mt < 4; mt++) O[mt][nt] = f32x4{0.f, 0.f, 0.f, 0.f};
  }

  // V stage: thread t fetches swizzled chunk so readback b128 is spread.
  const int sd = tid >> 3, ss = tid & 7;
  const int sc0 = (ss ^ (sd & 7)) * 8;
  const int sc1 = (ss ^ ((sd + 32) & 7)) * 8;

#define STAGE_V(p, kt)                                                          \
  do {                                                                          \
    GLDS16(vp + (size_t)sd * N_ + (kt) * 64 + sc0, &Vs[p][tid * 8]);            \
    GLDS16(vp + (size_t)(sd + 32) * N_ + (kt) * 64 + sc1,                       \
           &Vs[p][(tid + 256) * 8]);                                            \
  } while (0)

  STAGE_V(0, 0);

  for (int kt = 0; kt < 16; kt++) {
    const int p = kt & 1;
    __syncthreads();  // drains this tile's DMA; protects buffer reuse
    if (kt < 15) STAGE_V(p ^ 1, kt + 1);

    // K A-fragments for 4 S-tiles (direct global, permuted rows)
    bf16x8 kf[4][2];
#pragma unroll
    for (int u = 0; u < 4; u++) {
      int krow = kt * 64 + 32 * (u >> 1) + 4 * (u & 1) + krow_base;
      const unsigned short* kr = qkrow + (size_t)krow * 1024 + 512 + hh * 64;
#pragma unroll
      for (int ks = 0; ks < 2; ks++)
        kf[u][ks] = *(const bf16x8*)(kr + ks * 32 + quad * 8);
    }

    // V A-fragments: Vs[d][key], chunk-swizzled b128
    bf16x8 vf[4][2];
#pragma unroll
    for (int mt = 0; mt < 4; mt++) {
      int d = 16 * mt + col;
#pragma unroll
      for (int s = 0; s < 2; s++)
        vf[mt][s] = *(const bf16x8*)&Vs[p][d * 64 + (((4 * s + quad) ^ (d & 7)) << 3)];
    }

#pragma unroll
    for (int nt = 0; nt < 4; nt++) {
#pragma unroll
      for (int s = 0; s < 2; s++) {
        f32x4 sfA = f32x4{0.f, 0.f, 0.f, 0.f};
        f32x4 sfB = f32x4{0.f, 0.f, 0.f, 0.f};
#pragma unroll
        for (int ks = 0; ks < 2; ks++) {
          sfA = __builtin_amdgcn_mfma_f32_16x16x32_bf16(kf[2 * s][ks], qf[nt][ks], sfA, 0, 0, 0);
          sfB = __builtin_amdgcn_mfma_f32_16x16x32_bf16(kf[2 * s + 1][ks], qf[nt][ks], sfB, 0, 0, 0);
        }
        float eA0 = __builtin_amdgcn_exp2f(sfA[0]);
        float eA1 = __builtin_amdgcn_exp2f(sfA[1]);
        float eA2 = __builtin_amdgcn_exp2f(sfA[2]);
        float eA3 = __builtin_amdgcn_exp2f(sfA[3]);
        float eB0 = __builtin_amdgcn_exp2f(sfB[0]);
        float eB1 = __builtin_amdgcn_exp2f(sfB[1]);
        float eB2 = __builtin_amdgcn_exp2f(sfB[2]);
        float eB3 = __builtin_amdgcn_exp2f(sfB[3]);
        l_i[nt] += ((eA0 + eA1) + (eA2 + eA3)) + ((eB0 + eB1) + (eB2 + eB3));
        union { unsigned u[4]; bf16x8 v; } pf;
        pf.u[0] = __builtin_amdgcn_perm(__float_as_uint(eA1), __float_as_uint(eA0), 0x07060302u);
        pf.u[1] = __builtin_amdgcn_perm(__float_as_uint(eA3), __float_as_uint(eA2), 0x07060302u);
        pf.u[2] = __builtin_amdgcn_perm(__float_as_uint(eB1), __float_as_uint(eB0), 0x07060302u);
        pf.u[3] = __builtin_amdgcn_perm(__float_as_uint(eB3), __float_as_uint(eB2), 0x07060302u);
#pragma unroll
        for (int mt = 0; mt < 4; mt++)
          O[mt][nt] = __builtin_amdgcn_mfma_f32_16x16x32_bf16(vf[mt][s], pf.v, O[mt][nt], 0, 0, 0);
      }
    }
  }

#pragma unroll
  for (int nt = 0; nt < 4; nt++) {
    float ls = l_i[nt];
    ls += __shfl_xor(ls, 16, 64);
    ls += __shfl_xor(ls, 32, 64);
    float inv = 1.f / ls;
    int qg = qblk + nt * 16 + col;
    unsigned short* dst = aoT + ((size_t)b * N_ + qg) * C_ + hh * 64;
#pragma unroll
    for (int mt = 0; mt < 4; mt++) {
      union { unsigned short s[4]; ushort4 v; } o;
#pragma unroll
      for (int r = 0; r < 4; r++) o.s[r] = f2bf(O[mt][nt][r] * inv);
      *(ushort4*)(dst + mt * 16 + quad * 4) = o.v;
    }
  }
#undef STAGE_V
}

extern "C" void kernel_launch(void* const* d_in, const int* in_sizes, int n_in,
                              void* d_out, int out_size, void* d_ws, size_t ws_size,
                              hipStream_t stream) {
  (void)in_sizes; (void)n_in; (void)out_size; (void)ws_size;
  const float* x      = (const float*)d_in[0];
  const float* gamma  = (const float*)d_in[1];
  const float* beta   = (const float*)d_in[2];
  const float* w_qkv  = (const float*)d_in[3];
  const float* b_qkv  = (const float*)d_in[4];
  const float* w_proj = (const float*)d_in[5];
  const float* b_proj = (const float*)d_in[6];
  float* out = (float*)d_out;

  unsigned short* hT  = (unsigned short*)d_ws;            // B*N*512 bf16
  unsigned short* qkT = hT + (size_t)B_ * N_ * C_;        // B*N*1024 bf16
  unsigned short* Vb  = qkT + (size_t)B_ * N_ * 1024;     // B*512*N bf16
  unsigned short* aoT = hT;                               // reuse
  unsigned short* wqb = Vb + (size_t)B_ * C_ * N_;        // 1536*512 bf16
  unsigned short* wpb = wqb + (size_t)1536 * 512;         // 512*512 bf16

  wconv_kernel<<<dim3(1024), dim3(256), 0, stream>>>(w_qkv, w_proj, wqb, wpb);
  gn_kernel<<<dim3(B_ * 32), dim3(256), 0, stream>>>(x, gamma, beta, hT);
  gemm_mfma<1><<<dim3(8, 12, 16), dim3(256), 0, stream>>>(
      wqb, b_qkv, hT, (const float*)nullptr, (void*)qkT, (void*)Vb, 1536);
  attn_mfma<<<dim3(4, 8, 16), dim3(256), 0, stream>>>(qkT, Vb, aoT);
  gemm_mfma<0><<<dim3(8, 4, 16), dim3(256), 0, stream>>>(
      wpb, b_proj, aoT, x, (void*)out, (void*)nullptr, 512);
}

// Round 6
// 239.347 us; speedup vs baseline: 1.0025x; 1.0025x over previous
//
#include <hip/hip_runtime.h>
#include <cstddef>

#define B_  16
#define C_  512
#define N_  1024
// 0.125 * log2(e): folded into Q in the QKV GEMM epilogue; attn uses exp2.
#define QSC 0.18033688011112042f

typedef __attribute__((ext_vector_type(8))) __bf16 bf16x8;
typedef __attribute__((ext_vector_type(4))) float f32x4;

__device__ __forceinline__ unsigned short f2bf(float x) {
  unsigned u = __float_as_uint(x);
  return (unsigned short)((u + 0x7fffu + ((u >> 16) & 1u)) >> 16);
}

#define GLDS16(g, l)                                                            \
  __builtin_amdgcn_global_load_lds(                                             \
      (const __attribute__((address_space(1))) void*)(g),                       \
      (__attribute__((address_space(3))) void*)(l), 16, 0, 0)

// ---------- weight fp32 -> bf16 ----------
__global__ __launch_bounds__(256) void wconv_kernel(
    const float* __restrict__ wq, const float* __restrict__ wp,
    unsigned short* __restrict__ oq, unsigned short* __restrict__ op) {
  int i = blockIdx.x * 256 + threadIdx.x;
  const float4* src; unsigned short* dst; int off;
  if (i < 196608) { src = (const float4*)wq; dst = oq; off = i; }
  else            { src = (const float4*)wp; dst = op; off = i - 196608; }
  float4 v = src[off];
  union { unsigned short s[4]; ushort4 u; } o;
  o.s[0] = f2bf(v.x); o.s[1] = f2bf(v.y);
  o.s[2] = f2bf(v.z); o.s[3] = f2bf(v.w);
  *(ushort4*)(dst + (size_t)off * 4) = o.u;
}

// ---------- GroupNorm: writes hT[b][n][c] bf16 ----------
__global__ __launch_bounds__(256) void gn_kernel(
    const float* __restrict__ x, const float* __restrict__ gamma,
    const float* __restrict__ beta, unsigned short* __restrict__ hT) {
  int bg = blockIdx.x;
  int b = bg >> 5, g = bg & 31;
  size_t base = ((size_t)b * C_ + (size_t)g * 16) * N_;
  const float4* x4 = (const float4*)(x + base);
  int tid = threadIdx.x;

  float sum = 0.f, sq = 0.f;
  float4 vv[16];
#pragma unroll
  for (int i = 0; i < 16; i++) {
    float4 v = x4[tid + i * 256];
    vv[i] = v;
    sum += v.x + v.y + v.z + v.w;
    sq  += v.x * v.x + v.y * v.y + v.z * v.z + v.w * v.w;
  }
#pragma unroll
  for (int off = 32; off > 0; off >>= 1) {
    sum += __shfl_down(sum, off, 64);
    sq  += __shfl_down(sq, off, 64);
  }
  __shared__ float sm[4], sv[4];
  int lane = tid & 63, w = tid >> 6;
  if (lane == 0) { sm[w] = sum; sv[w] = sq; }
  __syncthreads();
  if (tid == 0) {
    float s = sm[0] + sm[1] + sm[2] + sm[3];
    float q = sv[0] + sv[1] + sv[2] + sv[3];
    float mean = s * (1.f / 16384.f);
    float var  = q * (1.f / 16384.f) - mean * mean;
    sm[0] = mean;
    sv[0] = rsqrtf(var + 1e-5f);
  }
  __syncthreads();
  float mean = sm[0], rstd = sv[0];

  union { unsigned short s[16]; uint4 u[2]; } row[4];
#pragma unroll
  for (int i = 0; i < 16; i++) {
    int c = g * 16 + i;
    float ga = gamma[c] * rstd;
    float be = beta[c] - mean * ga;
    float4 v = vv[i];
    row[0].s[i] = f2bf(v.x * ga + be);
    row[1].s[i] = f2bf(v.y * ga + be);
    row[2].s[i] = f2bf(v.z * ga + be);
    row[3].s[i] = f2bf(v.w * ga + be);
  }
#pragma unroll
  for (int j = 0; j < 4; j++) {
    uint4* dst = (uint4*)(hT + ((size_t)b * N_ + 4 * tid + j) * C_ + g * 16);
    dst[0] = row[j].u[0];
    dst[1] = row[j].u[1];
  }
}

// ---------- MFMA GEMM, m97 structure ----------
// MODE 0 (proj): fp32 Out[b,m,n] = acc + bias + resid.
// MODE 1 (qkv):  blockIdx.y<8 -> bf16 transposed qkT[b][n][m] (Q scaled QSC),
//                stored coalesced via LDS transpose; else bf16 Vb[b][m-1024][n].
template <int MODE>
__global__ __launch_bounds__(256) void gemm_mfma(
    const unsigned short* __restrict__ Wb, const float* __restrict__ bias,
    const unsigned short* __restrict__ InT, const float* __restrict__ resid,
    void* __restrict__ Out, void* __restrict__ Out2, int M) {
  __shared__ __align__(16) unsigned short smem[(MODE == 1) ? 128 * 136 : 8192];
  unsigned short* As = smem;
  unsigned short* Bs = smem + 4096;

  const int b = blockIdx.z;
  const int n0 = blockIdx.x * 128, m0 = blockIdx.y * 128;
  const int tid = threadIdx.x;
  const int lane = tid & 63, wave = tid >> 6;
  const int col = lane & 15, quad = lane >> 4;
  const int wm = (wave >> 1) << 6, wn = (wave & 1) << 6;

  const unsigned short* Ag = Wb + (size_t)m0 * C_;
  const unsigned short* Bg = InT + ((size_t)b * N_ + n0) * C_;

  const int r0 = tid >> 2, c0 = (tid & 3) << 3;

  f32x4 acc[4][4];
#pragma unroll
  for (int i = 0; i < 4; i++)
#pragma unroll
    for (int j = 0; j < 4; j++) acc[i][j] = f32x4{0.f, 0.f, 0.f, 0.f};

  for (int k0 = 0; k0 < C_; k0 += 32) {
    __syncthreads();
    GLDS16(Ag + (size_t)r0 * C_ + k0 + c0,        &As[tid * 8]);
    GLDS16(Ag + (size_t)(r0 + 64) * C_ + k0 + c0, &As[(tid + 256) * 8]);
    GLDS16(Bg + (size_t)r0 * C_ + k0 + c0,        &Bs[tid * 8]);
    GLDS16(Bg + (size_t)(r0 + 64) * C_ + k0 + c0, &Bs[(tid + 256) * 8]);
    __syncthreads();

    bf16x8 af[4], bfr[4];
#pragma unroll
    for (int mt = 0; mt < 4; mt++)
      af[mt] = *(const bf16x8*)&As[(wm + mt * 16 + col) * 32 + quad * 8];
#pragma unroll
    for (int nt = 0; nt < 4; nt++)
      bfr[nt] = *(const bf16x8*)&Bs[(wn + nt * 16 + col) * 32 + quad * 8];
#pragma unroll
    for (int mt = 0; mt < 4; mt++)
#pragma unroll
      for (int nt = 0; nt < 4; nt++)
        acc[mt][nt] = __builtin_amdgcn_mfma_f32_16x16x32_bf16(
            af[mt], bfr[nt], acc[mt][nt], 0, 0, 0);
  }

  if constexpr (MODE == 0) {
#pragma unroll
    for (int mt = 0; mt < 4; mt++) {
      int mbase = m0 + wm + mt * 16 + quad * 4;
#pragma unroll
      for (int nt = 0; nt < 4; nt++) {
        int n = n0 + wn + nt * 16 + col;
#pragma unroll
        for (int r = 0; r < 4; r++) {
          int m = mbase + r;
          size_t off = ((size_t)b * M + m) * N_ + n;
          ((float*)Out)[off] = acc[mt][nt][r] + bias[m] + resid[off];
        }
      }
    }
  } else {
    if (blockIdx.y < 8) {  // Q or K -> transposed qkT[b][n][1024], coalesced
      float qs = (blockIdx.y < 4) ? QSC : 1.0f;
      __syncthreads();  // As/Bs reads done; reuse smem as T[128n][136]
#pragma unroll
      for (int mt = 0; mt < 4; mt++) {
        int lm = wm + mt * 16 + quad * 4;
#pragma unroll
        for (int nt = 0; nt < 4; nt++) {
          int ln = wn + nt * 16 + col;
          union { unsigned short s[4]; ushort4 v; } o;
#pragma unroll
          for (int r = 0; r < 4; r++)
            o.s[r] = f2bf((acc[mt][nt][r] + bias[m0 + lm + r]) * qs);
          *(ushort4*)&smem[ln * 136 + lm] = o.v;
        }
      }
      __syncthreads();
      const int c = tid & 15, rr = tid >> 4;
#pragma unroll
      for (int i = 0; i < 8; i++) {
        int row = rr + i * 16;
        uint4 v = *(const uint4*)&smem[row * 136 + c * 8];
        *(uint4*)((unsigned short*)Out +
                  ((size_t)b * N_ + n0 + row) * 1024 + m0 + c * 8) = v;
      }
    } else {  // V -> natural Vb[b][m-1024][n]
#pragma unroll
      for (int mt = 0; mt < 4; mt++) {
        int mbase = m0 + wm + mt * 16 + quad * 4;
#pragma unroll
        for (int nt = 0; nt < 4; nt++) {
          int n = n0 + wn + nt * 16 + col;
#pragma unroll
          for (int r = 0; r < 4; r++) {
            int m = mbase + r;
            ((unsigned short*)Out2)[((size_t)b * 512 + (m - 1024)) * N_ + n] =
                f2bf(acc[mt][nt][r] + bias[m]);
          }
        }
      }
    }
  }
}

// ---------- MFMA flash attention v4: K register double-buffer, l via MFMA ----------
__global__ __launch_bounds__(256) void attn_mfma(
    const unsigned short* __restrict__ qkT, const unsigned short* __restrict__ Vb,
    unsigned short* __restrict__ aoT) {
  __shared__ __align__(16) unsigned short Vs[2][64 * 64];

  const int tid = threadIdx.x;
  const int wave = tid >> 6, lane = tid & 63;
  const int quad = lane >> 4, col = lane & 15;
  const int b = blockIdx.z, hh = blockIdx.y;
  const int qblk = blockIdx.x * 256 + wave * 64;

  const unsigned short* qkrow = qkT + (size_t)b * N_ * 1024;
  const unsigned short* vp = Vb + ((size_t)b * 512 + hh * 64) * N_;

  bf16x8 qf[4][2];
#pragma unroll
  for (int nt = 0; nt < 4; nt++) {
    const unsigned short* qr = qkrow + (size_t)(qblk + nt * 16 + col) * 1024 + hh * 64;
#pragma unroll
    for (int ks = 0; ks < 2; ks++)
      qf[nt][ks] = *(const bf16x8*)(qr + ks * 32 + quad * 8);
  }

  const int krow_base = 8 * (col >> 2) + (col & 3);

  f32x4 O[4][4], lacc[4];
#pragma unroll
  for (int nt = 0; nt < 4; nt++) {
    lacc[nt] = f32x4{0.f, 0.f, 0.f, 0.f};
#pragma unroll
    for (int mt = 0; mt < 4; mt++) O[mt][nt] = f32x4{0.f, 0.f, 0.f, 0.f};
  }

  union { unsigned short s[8]; bf16x8 v; } one8;
#pragma unroll
  for (int j = 0; j < 8; j++) one8.s[j] = 0x3F80;  // bf16 1.0

  const int sd = tid >> 3, ss = tid & 7;
  const int sc0 = (ss ^ (sd & 7)) * 8;
  const int sc1 = (ss ^ ((sd + 32) & 7)) * 8;

#define STAGE_V(p, kt)                                                          \
  do {                                                                          \
    GLDS16(vp + (size_t)sd * N_ + (kt) * 64 + sc0, &Vs[p][tid * 8]);            \
    GLDS16(vp + (size_t)(sd + 32) * N_ + (kt) * 64 + sc1,                       \
           &Vs[p][(tid + 256) * 8]);                                            \
  } while (0)

#define LOADK(dst, kt)                                                          \
  do {                                                                          \
    _Pragma("unroll")                                                           \
    for (int u = 0; u < 4; u++) {                                               \
      int krow = (kt) * 64 + 32 * (u >> 1) + 4 * (u & 1) + krow_base;           \
      const unsigned short* kr = qkrow + (size_t)krow * 1024 + 512 + hh * 64;   \
      dst[u][0] = *(const bf16x8*)(kr + quad * 8);                              \
      dst[u][1] = *(const bf16x8*)(kr + 32 + quad * 8);                         \
    }                                                                           \
  } while (0)

#define TILE(kt, P, KC, KN)                                                     \
  do {                                                                          \
    __syncthreads();                                                            \
    if ((kt) < 15) { STAGE_V((P) ^ 1, (kt) + 1); LOADK(KN, (kt) + 1); }         \
    bf16x8 vf[4][2];                                                            \
    _Pragma("unroll")                                                           \
    for (int mt = 0; mt < 4; mt++) {                                            \
      int d = 16 * mt + col;                                                    \
      _Pragma("unroll")                                                         \
      for (int s = 0; s < 2; s++)                                               \
        vf[mt][s] = *(const bf16x8*)&Vs[P][d * 64 + (((4 * s + quad) ^ (d & 7)) << 3)]; \
    }                                                                           \
    _Pragma("unroll")                                                           \
    for (int nt = 0; nt < 4; nt++) {                                            \
      _Pragma("unroll")                                                         \
      for (int s = 0; s < 2; s++) {                                             \
        f32x4 sfA = f32x4{0.f, 0.f, 0.f, 0.f};                                  \
        f32x4 sfB = f32x4{0.f, 0.f, 0.f, 0.f};                                  \
        _Pragma("unroll")                                                       \
        for (int ks = 0; ks < 2; ks++) {                                        \
          sfA = __builtin_amdgcn_mfma_f32_16x16x32_bf16(KC[2 * s][ks], qf[nt][ks], sfA, 0, 0, 0);     \
          sfB = __builtin_amdgcn_mfma_f32_16x16x32_bf16(KC[2 * s + 1][ks], qf[nt][ks], sfB, 0, 0, 0); \
        }                                                                       \
        float eA0 = __builtin_amdgcn_exp2f(sfA[0]);                             \
        float eA1 = __builtin_amdgcn_exp2f(sfA[1]);                             \
        float eA2 = __builtin_amdgcn_exp2f(sfA[2]);                             \
        float eA3 = __builtin_amdgcn_exp2f(sfA[3]);                             \
        float eB0 = __builtin_amdgcn_exp2f(sfB[0]);                             \
        float eB1 = __builtin_amdgcn_exp2f(sfB[1]);                             \
        float eB2 = __builtin_amdgcn_exp2f(sfB[2]);                             \
        float eB3 = __builtin_amdgcn_exp2f(sfB[3]);                             \
        union { unsigned u[4]; bf16x8 v; } pf;                                  \
        pf.u[0] = __builtin_amdgcn_perm(__float_as_uint(eA1), __float_as_uint(eA0), 0x07060302u); \
        pf.u[1] = __builtin_amdgcn_perm(__float_as_uint(eA3), __float_as_uint(eA2), 0x07060302u); \
        pf.u[2] = __builtin_amdgcn_perm(__float_as_uint(eB1), __float_as_uint(eB0), 0x07060302u); \
        pf.u[3] = __builtin_amdgcn_perm(__float_as_uint(eB3), __float_as_uint(eB2), 0x07060302u); \
        lacc[nt] = __builtin_amdgcn_mfma_f32_16x16x32_bf16(one8.v, pf.v, lacc[nt], 0, 0, 0);      \
        _Pragma("unroll")                                                       \
        for (int mt = 0; mt < 4; mt++)                                          \
          O[mt][nt] = __builtin_amdgcn_mfma_f32_16x16x32_bf16(vf[mt][s], pf.v, O[mt][nt], 0, 0, 0); \
      }                                                                         \
    }                                                                           \
  } while (0)

  bf16x8 kfa[4][2], kfb[4][2];
  LOADK(kfa, 0);
  STAGE_V(0, 0);

#pragma unroll 1
  for (int kt2 = 0; kt2 < 8; kt2++) {
    TILE(2 * kt2, 0, kfa, kfb);
    TILE(2 * kt2 + 1, 1, kfb, kfa);
  }

#pragma unroll
  for (int nt = 0; nt < 4; nt++) {
    float inv = 1.f / lacc[nt][0];
    int qg = qblk + nt * 16 + col;
    unsigned short* dst = aoT + ((size_t)b * N_ + qg) * C_ + hh * 64;
#pragma unroll
    for (int mt = 0; mt < 4; mt++) {
      union { unsigned short s[4]; ushort4 v; } o;
#pragma unroll
      for (int r = 0; r < 4; r++) o.s[r] = f2bf(O[mt][nt][r] * inv);
      *(ushort4*)(dst + mt * 16 + quad * 4) = o.v;
    }
  }
#undef STAGE_V
#undef LOADK
#undef TILE
}

extern "C" void kernel_launch(void* const* d_in, const int* in_sizes, int n_in,
                              void* d_out, int out_size, void* d_ws, size_t ws_size,
                              hipStream_t stream) {
  (void)in_sizes; (void)n_in; (void)out_size; (void)ws_size;
  const float* x      = (const float*)d_in[0];
  const float* gamma  = (const float*)d_in[1];
  const float* beta   = (const float*)d_in[2];
  const float* w_qkv  = (const float*)d_in[3];
  const float* b_qkv  = (const float*)d_in[4];
  const float* w_proj = (const float*)d_in[5];
  const float* b_proj = (const float*)d_in[6];
  float* out = (float*)d_out;

  unsigned short* hT  = (unsigned short*)d_ws;            // B*N*512 bf16
  unsigned short* qkT = hT + (size_t)B_ * N_ * C_;        // B*N*1024 bf16
  unsigned short* Vb  = qkT + (size_t)B_ * N_ * 1024;     // B*512*N bf16
  unsigned short* aoT = hT;                               // reuse
  unsigned short* wqb = Vb + (size_t)B_ * C_ * N_;        // 1536*512 bf16
  unsigned short* wpb = wqb + (size_t)1536 * 512;         // 512*512 bf16

  wconv_kernel<<<dim3(1024), dim3(256), 0, stream>>>(w_qkv, w_proj, wqb, wpb);
  gn_kernel<<<dim3(B_ * 32), dim3(256), 0, stream>>>(x, gamma, beta, hT);
  gemm_mfma<1><<<dim3(8, 12, 16), dim3(256), 0, stream>>>(
      wqb, b_qkv, hT, (const float*)nullptr, (void*)qkT, (void*)Vb, 1536);
  attn_mfma<<<dim3(4, 8, 16), dim3(256), 0, stream>>>(qkT, Vb, aoT);
  gemm_mfma<0><<<dim3(8, 4, 16), dim3(256), 0, stream>>>(
      wpb, b_proj, aoT, x, (void*)out, (void*)nullptr, 512);
}